// Round 1
// baseline (3663.852 us; speedup 1.0000x reference)
//
#include <hip/hip_runtime.h>
#include <math.h>

#define N_EMBD    1024
#define N_HEAD    16
#define HEAD_SIZE 64
#define T_SEQ     2048
#define BATCH     2
#define HIDDEN    2048
#define ROWS      (BATCH * T_SEQ)   // 4096

// ---------------- LayerNorm (one block per row, float4) ----------------
__global__ __launch_bounds__(256) void ln_kernel(const float* __restrict__ x,
                                                 const float* __restrict__ w,
                                                 const float* __restrict__ b,
                                                 float* __restrict__ out)
{
    const int row = blockIdx.x;
    const int tid = threadIdx.x;
    const float* xr = x + (size_t)row * N_EMBD;
    float4 v = *(const float4*)(xr + tid * 4);
    float s  = v.x + v.y + v.z + v.w;
    float s2 = v.x*v.x + v.y*v.y + v.z*v.z + v.w*v.w;
#pragma unroll
    for (int off = 32; off; off >>= 1) {
        s  += __shfl_xor(s, off);
        s2 += __shfl_xor(s2, off);
    }
    __shared__ float ss[4], ss2[4];
    if ((tid & 63) == 0) { ss[tid >> 6] = s; ss2[tid >> 6] = s2; }
    __syncthreads();
    s  = ss[0] + ss[1] + ss[2] + ss[3];
    s2 = ss2[0] + ss2[1] + ss2[2] + ss2[3];
    const float mean = s * (1.0f / N_EMBD);
    const float var  = s2 * (1.0f / N_EMBD) - mean * mean;
    const float rstd = rsqrtf(var + 1e-5f);
    float4 wv = *(const float4*)(w + tid * 4);
    float4 bv = *(const float4*)(b + tid * 4);
    float4 o;
    o.x = (v.x - mean) * rstd * wv.x + bv.x;
    o.y = (v.y - mean) * rstd * wv.y + bv.y;
    o.z = (v.z - mean) * rstd * wv.z + bv.z;
    o.w = (v.w - mean) * rstd * wv.w + bv.w;
    *(float4*)(out + (size_t)row * N_EMBD + tid * 4) = o;
}

// ---------------- QKV projection: h[4096x1024] x W[which][head][1024x64] ----------------
// grid.x = 48 (which*16+head), grid.y = ROWS/64. Output layout [B,H,T,D].
__global__ __launch_bounds__(256) void qkv_kernel(const float* __restrict__ hin,
                                                  const float* __restrict__ Wq,
                                                  const float* __restrict__ Wk,
                                                  const float* __restrict__ Wv,
                                                  float* __restrict__ qo,
                                                  float* __restrict__ ko,
                                                  float* __restrict__ vo)
{
    __shared__ float As[16][64];
    __shared__ float Bs[16][64];
    const int wh    = blockIdx.x;
    const int which = wh >> 4;
    const int head  = wh & 15;
    const int m0    = blockIdx.y * 64;
    const float* W  = (which == 0 ? Wq : (which == 1 ? Wk : Wv)) + (size_t)head * N_EMBD * HEAD_SIZE;
    float* out      = (which == 0 ? qo : (which == 1 ? ko : vo));
    const int tid = threadIdx.x;
    const int tx = tid & 15, ty = tid >> 4;
    float acc[4][4] = {};
    for (int k0 = 0; k0 < N_EMBD; k0 += 16) {
        float4 av = *(const float4*)(hin + (size_t)(m0 + (tid >> 2)) * N_EMBD + k0 + (tid & 3) * 4);
        As[(tid & 3) * 4 + 0][tid >> 2] = av.x;
        As[(tid & 3) * 4 + 1][tid >> 2] = av.y;
        As[(tid & 3) * 4 + 2][tid >> 2] = av.z;
        As[(tid & 3) * 4 + 3][tid >> 2] = av.w;
        float4 bv = *(const float4*)(W + (size_t)(k0 + (tid >> 4)) * HEAD_SIZE + (tid & 15) * 4);
        *(float4*)&Bs[tid >> 4][(tid & 15) * 4] = bv;
        __syncthreads();
#pragma unroll
        for (int kk = 0; kk < 16; kk++) {
            float4 a  = *(const float4*)&As[kk][ty * 4];
            float4 bb = *(const float4*)&Bs[kk][tx * 4];
            float ar[4] = {a.x, a.y, a.z, a.w};
            float br[4] = {bb.x, bb.y, bb.z, bb.w};
#pragma unroll
            for (int i = 0; i < 4; i++)
#pragma unroll
                for (int j = 0; j < 4; j++)
                    acc[i][j] += ar[i] * br[j];
        }
        __syncthreads();
    }
#pragma unroll
    for (int i = 0; i < 4; i++) {
        const int m = m0 + ty * 4 + i;
        const int bidx = m >> 11;          // /T_SEQ
        const int t    = m & (T_SEQ - 1);
        const size_t obase = (((size_t)(bidx * N_HEAD + head)) * T_SEQ + t) * HEAD_SIZE;
        float4 ov = make_float4(acc[i][0], acc[i][1], acc[i][2], acc[i][3]);
        *(float4*)(out + obase + tx * 4) = ov;
    }
}

// ---------------- RoPE (matches reference: angle_j = t * inv_freq[j & 31], interleaved rotate_half) --------
__global__ __launch_bounds__(256) void rope_kernel(float* __restrict__ q, float* __restrict__ k)
{
    const int u = blockIdx.x * 256 + threadIdx.x;   // [0, B*H*T*32)
    const int i  = u & 31;
    const int t  = (u >> 5) & (T_SEQ - 1);
    const int bh = u >> 16;
    const size_t base = ((size_t)bh * T_SEQ + t) * HEAD_SIZE;
    const float LOG1E4_32 = 0.28782313662425572f;   // ln(10000)/32
    const int i0 = (2 * i) & 31;
    const int i1 = (2 * i + 1) & 31;
    const float f0 = __expf(-(float)i0 * LOG1E4_32);
    const float f1 = __expf(-(float)i1 * LOG1E4_32);
    const float a0 = (float)t * f0;
    const float a1 = (float)t * f1;
    float c0, s0, c1, s1;
    sincosf(a0, &s0, &c0);
    sincosf(a1, &s1, &c1);
    float q0 = q[base + 2 * i], q1 = q[base + 2 * i + 1];
    q[base + 2 * i]     = q0 * c0 - q1 * s0;
    q[base + 2 * i + 1] = q1 * c1 + q0 * s1;
    float k0 = k[base + 2 * i], k1 = k[base + 2 * i + 1];
    k[base + 2 * i]     = k0 * c0 - k1 * s0;
    k[base + 2 * i + 1] = k1 * c1 + k0 * s1;
}

// ---------------- Flash attention: 1 wave per query row, 4 rows/block share K-chunk in LDS --------
__global__ __launch_bounds__(256) void attn_kernel(const float* __restrict__ q,
                                                   const float* __restrict__ k,
                                                   const float* __restrict__ v,
                                                   float* __restrict__ o)
{
    __shared__ float Ks[64][68];   // +4 float pad to break stride-256B bank conflicts
    const int widx = threadIdx.x >> 6;
    const int lane = threadIdx.x & 63;
    const int t0 = (blockIdx.x & (T_SEQ / 4 - 1)) * 4;
    const int bh = blockIdx.x >> 9;   // / (T_SEQ/4)
    const int t  = t0 + widx;
    const float* kbase = k + (size_t)bh * T_SEQ * HEAD_SIZE;
    const float* vbase = v + (size_t)bh * T_SEQ * HEAD_SIZE;
    const float qv = q[((size_t)bh * T_SEQ + t) * HEAD_SIZE + lane] * 0.125f;  // 1/sqrt(64)
    float m = -INFINITY, l = 0.f, acc = 0.f;
    const int tmax = t0 + 3;
    for (int s0 = 0; s0 <= tmax; s0 += 64) {
        __syncthreads();
#pragma unroll
        for (int rep = 0; rep < 4; rep++) {
            const int f = rep * 256 + threadIdx.x;      // float4 index in 64x64 chunk
            const int row = f >> 4, col = (f & 15) * 4;
            float4 kv = *(const float4*)(kbase + (size_t)(s0 + row) * HEAD_SIZE + col);
            *(float4*)&Ks[row][col] = kv;
        }
        __syncthreads();
        if (s0 <= t) {
            const int s = s0 + lane;
            float score = 0.f;
#pragma unroll
            for (int d0 = 0; d0 < 64; d0 += 4) {
                float4 kv4 = *(const float4*)&Ks[lane][d0];
                score += __shfl(qv, d0 + 0) * kv4.x;
                score += __shfl(qv, d0 + 1) * kv4.y;
                score += __shfl(qv, d0 + 2) * kv4.z;
                score += __shfl(qv, d0 + 3) * kv4.w;
            }
            float sc = (s <= t) ? score : -INFINITY;
            float cmax = sc;
#pragma unroll
            for (int off = 32; off; off >>= 1) cmax = fmaxf(cmax, __shfl_xor(cmax, off));
            const float mnew  = fmaxf(m, cmax);
            const float p     = (s <= t) ? __expf(score - mnew) : 0.f;
            const float alpha = __expf(m - mnew);     // exp(-inf)=0 on first chunk
            float psum = p;
#pragma unroll
            for (int off = 32; off; off >>= 1) psum += __shfl_xor(psum, off);
            l = l * alpha + psum;
            acc *= alpha;
            const int jmax = min(63, t - s0);
            for (int j = 0; j <= jmax; j++) {
                const float pj = __shfl(p, j);
                acc += pj * vbase[(size_t)(s0 + j) * HEAD_SIZE + lane];
            }
            m = mnew;
        }
    }
    const int b = bh >> 4, hh = bh & 15;
    o[((size_t)(b * T_SEQ + t)) * N_EMBD + hh * HEAD_SIZE + lane] = acc / l;
}

// ---------------- GEMM + bias + residual: C = A[MxK] @ B[KxN] + bias + resid ----------------
__global__ __launch_bounds__(256) void gemm_br(const float* __restrict__ A,
                                               const float* __restrict__ B,
                                               const float* __restrict__ bias,
                                               const float* __restrict__ resid,
                                               float* __restrict__ C,
                                               int M, int N, int K)
{
    __shared__ float As[16][64];
    __shared__ float Bs[16][64];
    const int n0 = blockIdx.x * 64;
    const int m0 = blockIdx.y * 64;
    const int tid = threadIdx.x;
    const int tx = tid & 15, ty = tid >> 4;
    float acc[4][4] = {};
    for (int k0 = 0; k0 < K; k0 += 16) {
        float4 av = *(const float4*)(A + (size_t)(m0 + (tid >> 2)) * K + k0 + (tid & 3) * 4);
        As[(tid & 3) * 4 + 0][tid >> 2] = av.x;
        As[(tid & 3) * 4 + 1][tid >> 2] = av.y;
        As[(tid & 3) * 4 + 2][tid >> 2] = av.z;
        As[(tid & 3) * 4 + 3][tid >> 2] = av.w;
        float4 bv = *(const float4*)(B + (size_t)(k0 + (tid >> 4)) * N + n0 + (tid & 15) * 4);
        *(float4*)&Bs[tid >> 4][(tid & 15) * 4] = bv;
        __syncthreads();
#pragma unroll
        for (int kk = 0; kk < 16; kk++) {
            float4 a  = *(const float4*)&As[kk][ty * 4];
            float4 bb = *(const float4*)&Bs[kk][tx * 4];
            float ar[4] = {a.x, a.y, a.z, a.w};
            float br[4] = {bb.x, bb.y, bb.z, bb.w};
#pragma unroll
            for (int i = 0; i < 4; i++)
#pragma unroll
                for (int j = 0; j < 4; j++)
                    acc[i][j] += ar[i] * br[j];
        }
        __syncthreads();
    }
#pragma unroll
    for (int i = 0; i < 4; i++) {
        const int m = m0 + ty * 4 + i;
        const int n = n0 + tx * 4;
        float4 bi = *(const float4*)(bias + n);
        float4 rv = *(const float4*)(resid + (size_t)m * N + n);
        float4 ov;
        ov.x = acc[i][0] + bi.x + rv.x;
        ov.y = acc[i][1] + bi.y + rv.y;
        ov.z = acc[i][2] + bi.z + rv.z;
        ov.w = acc[i][3] + bi.w + rv.w;
        *(float4*)(C + (size_t)m * N + n) = ov;
    }
}

// ---------------- Fused GLU: g = silu(h2@w_w + w_b) * (h2@v_w + v_b) ----------------
__global__ __launch_bounds__(256) void mlp_gate_kernel(const float* __restrict__ A,
                                                       const float* __restrict__ Bw,
                                                       const float* __restrict__ Bv,
                                                       const float* __restrict__ wb,
                                                       const float* __restrict__ vb,
                                                       float* __restrict__ G)
{
    __shared__ float As[16][64];
    __shared__ float Ws[16][64];
    __shared__ float Vs[16][64];
    const int n0 = blockIdx.x * 64;
    const int m0 = blockIdx.y * 64;
    const int tid = threadIdx.x;
    const int tx = tid & 15, ty = tid >> 4;
    float accA[4][4] = {};
    float accB[4][4] = {};
    for (int k0 = 0; k0 < N_EMBD; k0 += 16) {
        float4 av = *(const float4*)(A + (size_t)(m0 + (tid >> 2)) * N_EMBD + k0 + (tid & 3) * 4);
        As[(tid & 3) * 4 + 0][tid >> 2] = av.x;
        As[(tid & 3) * 4 + 1][tid >> 2] = av.y;
        As[(tid & 3) * 4 + 2][tid >> 2] = av.z;
        As[(tid & 3) * 4 + 3][tid >> 2] = av.w;
        float4 wv = *(const float4*)(Bw + (size_t)(k0 + (tid >> 4)) * HIDDEN + n0 + (tid & 15) * 4);
        *(float4*)&Ws[tid >> 4][(tid & 15) * 4] = wv;
        float4 vv = *(const float4*)(Bv + (size_t)(k0 + (tid >> 4)) * HIDDEN + n0 + (tid & 15) * 4);
        *(float4*)&Vs[tid >> 4][(tid & 15) * 4] = vv;
        __syncthreads();
#pragma unroll
        for (int kk = 0; kk < 16; kk++) {
            float4 a  = *(const float4*)&As[kk][ty * 4];
            float4 w4 = *(const float4*)&Ws[kk][tx * 4];
            float4 v4 = *(const float4*)&Vs[kk][tx * 4];
            float ar[4] = {a.x, a.y, a.z, a.w};
            float wr[4] = {w4.x, w4.y, w4.z, w4.w};
            float vr[4] = {v4.x, v4.y, v4.z, v4.w};
#pragma unroll
            for (int i = 0; i < 4; i++)
#pragma unroll
                for (int j = 0; j < 4; j++) {
                    accA[i][j] += ar[i] * wr[j];
                    accB[i][j] += ar[i] * vr[j];
                }
        }
        __syncthreads();
    }
#pragma unroll
    for (int i = 0; i < 4; i++) {
        const int m = m0 + ty * 4 + i;
        const int n = n0 + tx * 4;
        float4 wbi = *(const float4*)(wb + n);
        float4 vbi = *(const float4*)(vb + n);
        float g[4];
#pragma unroll
        for (int j = 0; j < 4; j++) {
            float a  = accA[i][j] + ((const float*)&wbi)[j];
            float bb = accB[i][j] + ((const float*)&vbi)[j];
            float sig = 1.0f / (1.0f + __expf(-a));
            g[j] = a * sig * bb;
        }
        *(float4*)(G + (size_t)m * HIDDEN + n) = make_float4(g[0], g[1], g[2], g[3]);
    }
}

extern "C" void kernel_launch(void* const* d_in, const int* in_sizes, int n_in,
                              void* d_out, int out_size, void* d_ws, size_t ws_size,
                              hipStream_t stream)
{
    (void)in_sizes; (void)n_in; (void)out_size; (void)ws_size;
    const float* x      = (const float*)d_in[0];
    const float* ln1_w  = (const float*)d_in[1];
    const float* ln1_b  = (const float*)d_in[2];
    const float* ln2_w  = (const float*)d_in[3];
    const float* ln2_b  = (const float*)d_in[4];
    const float* Wq     = (const float*)d_in[5];
    const float* Wk     = (const float*)d_in[6];
    const float* Wv     = (const float*)d_in[7];
    const float* proj_w = (const float*)d_in[8];
    const float* proj_b = (const float*)d_in[9];
    const float* w_w    = (const float*)d_in[10];
    const float* w_b    = (const float*)d_in[11];
    const float* v_w    = (const float*)d_in[12];
    const float* v_b    = (const float*)d_in[13];
    const float* p_w    = (const float*)d_in[14];
    const float* p_b    = (const float*)d_in[15];
    float* out = (float*)d_out;

    float* ws = (float*)d_ws;
    const size_t NTOK = (size_t)ROWS * N_EMBD;   // 4,194,304 floats
    float* h  = ws;              // LN1 out, later x1
    float* q  = ws + NTOK;       // later g (uses q+k regions)
    float* kk = ws + 2 * NTOK;
    float* vv = ws + 3 * NTOK;
    float* o  = ws + 4 * NTOK;   // attn out, later h2

    // 1. LN1
    ln_kernel<<<ROWS, 256, 0, stream>>>(x, ln1_w, ln1_b, h);
    // 2. QKV
    qkv_kernel<<<dim3(3 * N_HEAD, ROWS / 64), 256, 0, stream>>>(h, Wq, Wk, Wv, q, kk, vv);
    // 3. RoPE on q,k
    rope_kernel<<<(BATCH * N_HEAD * T_SEQ * 32) / 256, 256, 0, stream>>>(q, kk);
    // 4. Attention -> o in [B,T,C]
    attn_kernel<<<(BATCH * N_HEAD * T_SEQ) / 4, 256, 0, stream>>>(q, kk, vv, o);
    // 5. proj + residual -> x1 (stored in h)
    gemm_br<<<dim3(N_EMBD / 64, ROWS / 64), 256, 0, stream>>>(o, proj_w, proj_b, x, h,
                                                              ROWS, N_EMBD, N_EMBD);
    // 6. LN2 -> h2 (stored in o)
    ln_kernel<<<ROWS, 256, 0, stream>>>(h, ln2_w, ln2_b, o);
    // 7. fused GLU -> g (stored in q..k regions)
    mlp_gate_kernel<<<dim3(HIDDEN / 64, ROWS / 64), 256, 0, stream>>>(o, w_w, v_w, w_b, v_b, q);
    // 8. final GEMM + bias + residual -> out
    gemm_br<<<dim3(N_EMBD / 64, ROWS / 64), 256, 0, stream>>>(q, p_w, p_b, h, out,
                                                              ROWS, N_EMBD, HIDDEN);
}

// Round 3
// 359.700 us; speedup vs baseline: 10.1859x; 10.1859x over previous
//
#include <hip/hip_runtime.h>
#include <math.h>

#define N_EMBD    1024
#define N_HEAD    16
#define HEAD_SIZE 64
#define T_SEQ     2048
#define BATCH     2
#define HIDDEN    2048
#define ROWS      4096

typedef __attribute__((ext_vector_type(8))) short bf16x8;
typedef __attribute__((ext_vector_type(4))) float f32x4;
typedef __attribute__((ext_vector_type(8))) unsigned short u16x8;
typedef unsigned short u16;

__device__ __forceinline__ u16 f2bf(float x) {
    union { float f; unsigned u; } v; v.f = x;
    unsigned r = v.u + 0x7fffu + ((v.u >> 16) & 1u);
    return (u16)(r >> 16);
}
__device__ __forceinline__ float bf2f(u16 h) {
    union { unsigned u; float f; } v; v.u = ((unsigned)h) << 16;
    return v.f;
}
__device__ __forceinline__ void gload16(const void* g, void* lds) {
    __builtin_amdgcn_global_load_lds((const __attribute__((address_space(1))) void*)g,
                                     (__attribute__((address_space(3))) void*)lds, 16, 0, 0);
}

// ---------------- weight transpose + bf16 cast: dst[n][k] = (bf16)src[k][n] ----------------
// grid: (K/64, N/64, Z). src row stride ldS, dst row stride ldD.
__global__ __launch_bounds__(256) void wtrans(const float* __restrict__ src, u16* __restrict__ dst,
                                              int ldS, int ldD, long srcZ, long dstZ)
{
    __shared__ float Ts[64][65];
    const float* s = src + (size_t)blockIdx.z * srcZ;
    u16* d = dst + (size_t)blockIdx.z * dstZ;
    const int k0 = blockIdx.x * 64, n0 = blockIdx.y * 64;
    const int tid = threadIdx.x;
    const int rr = tid >> 4, c4 = (tid & 15) * 4;
#pragma unroll
    for (int i = 0; i < 4; i++) {
        float4 v = *(const float4*)(s + (size_t)(k0 + rr + i * 16) * ldS + n0 + c4);
        Ts[rr + i * 16][c4 + 0] = v.x;
        Ts[rr + i * 16][c4 + 1] = v.y;
        Ts[rr + i * 16][c4 + 2] = v.z;
        Ts[rr + i * 16][c4 + 3] = v.w;
    }
    __syncthreads();
    const int nr = tid >> 2, kc = (tid & 3) * 16;
#pragma unroll
    for (int j = 0; j < 4; j++) {
        u16 t0 = f2bf(Ts[kc + j * 4 + 0][nr]);
        u16 t1 = f2bf(Ts[kc + j * 4 + 1][nr]);
        u16 t2 = f2bf(Ts[kc + j * 4 + 2][nr]);
        u16 t3 = f2bf(Ts[kc + j * 4 + 3][nr]);
        *(ushort4*)(d + (size_t)(n0 + nr) * ldD + k0 + kc + j * 4) = make_ushort4(t0, t1, t2, t3);
    }
}

// ---------------- LayerNorm f32 -> bf16 ----------------
__global__ __launch_bounds__(256) void ln_kernel(const float* __restrict__ x,
                                                 const float* __restrict__ w,
                                                 const float* __restrict__ b,
                                                 u16* __restrict__ out)
{
    const int row = blockIdx.x;
    const int tid = threadIdx.x;
    const float* xr = x + (size_t)row * N_EMBD;
    float4 v = *(const float4*)(xr + tid * 4);
    float s  = v.x + v.y + v.z + v.w;
    float s2 = v.x*v.x + v.y*v.y + v.z*v.z + v.w*v.w;
#pragma unroll
    for (int off = 32; off; off >>= 1) {
        s  += __shfl_xor(s, off);
        s2 += __shfl_xor(s2, off);
    }
    __shared__ float ss[4], ss2[4];
    if ((tid & 63) == 0) { ss[tid >> 6] = s; ss2[tid >> 6] = s2; }
    __syncthreads();
    s  = ss[0] + ss[1] + ss[2] + ss[3];
    s2 = ss2[0] + ss2[1] + ss2[2] + ss2[3];
    const float mean = s * (1.0f / N_EMBD);
    const float var  = s2 * (1.0f / N_EMBD) - mean * mean;
    const float rstd = rsqrtf(var + 1e-5f);
    float4 wv = *(const float4*)(w + tid * 4);
    float4 bv = *(const float4*)(b + tid * 4);
    ushort4 st = make_ushort4(f2bf((v.x - mean) * rstd * wv.x + bv.x),
                              f2bf((v.y - mean) * rstd * wv.y + bv.y),
                              f2bf((v.z - mean) * rstd * wv.z + bv.z),
                              f2bf((v.w - mean) * rstd * wv.w + bv.w));
    *(ushort4*)(out + (size_t)row * N_EMBD + tid * 4) = st;
}

// ---------------- RoPE on bf16 q,k (angle_j = t * inv_freq[j & 31], interleaved pairs) ----------------
__global__ __launch_bounds__(256) void rope_kernel(u16* __restrict__ q, u16* __restrict__ k)
{
    const int u = blockIdx.x * 256 + threadIdx.x;   // [0, B*H*T*32)
    const int i  = u & 31;
    const int t  = (u >> 5) & (T_SEQ - 1);
    const int bh = u >> 16;
    const size_t base = ((size_t)bh * T_SEQ + t) * HEAD_SIZE + 2 * i;
    const float L = 0.28782313662425572f;   // ln(10000)/32
    const int i0 = (2 * i) & 31, i1 = (2 * i + 1) & 31;
    float c0, s0, c1, s1;
    sincosf((float)t * __expf(-(float)i0 * L), &s0, &c0);
    sincosf((float)t * __expf(-(float)i1 * L), &s1, &c1);
    float a0 = bf2f(q[base]), a1 = bf2f(q[base + 1]);
    q[base]     = f2bf(a0 * c0 - a1 * s0);
    q[base + 1] = f2bf(a1 * c1 + a0 * s1);
    float b0 = bf2f(k[base]), b1 = bf2f(k[base + 1]);
    k[base]     = f2bf(b0 * c0 - b1 * s0);
    k[base + 1] = f2bf(b1 * c1 + b0 * s1);
}

// ---------------- MFMA GEMM core (128x128 tile, BK=32, 4 waves) ----------------
// A [4096][K] bf16 row-major; Bt [N][K] bf16 row-major (pre-transposed weights).
// mode 0: Cf[m][n] = acc + bias[n] + resid[m][n]   (f32 out)
// mode 1: Cb[m][n] = bf16(acc + bias[n])
// mode 2: g = silu(Cb[m][n]) * (acc + bias[n]); Cb[m][n] = bf16(g)   (in-place GLU)
__global__ __launch_bounds__(256) void gemm_br(const u16* __restrict__ A, const u16* __restrict__ Bt,
                                               const float* __restrict__ bias, const float* __restrict__ resid,
                                               float* __restrict__ Cf, u16* __restrict__ Cb,
                                               int N, int K, int mode)
{
    __shared__ __align__(16) u16 As[128 * 32];
    __shared__ __align__(16) u16 Bs[128 * 32];
    const int tid = threadIdx.x, w = tid >> 6, l = tid & 63, l15 = l & 15, l4 = l >> 4;
    const int wm = w >> 1, wn = w & 1;
    const int n0 = blockIdx.x * 128, m0 = blockIdx.y * 128;
    f32x4 acc[4][4] = {};
    for (int k0 = 0; k0 < K; k0 += 32) {
        __syncthreads();
#pragma unroll
        for (int c = 0; c < 2; c++) {
            const int i = w + c * 4;
            gload16(A  + (size_t)(m0 + i * 16 + (l >> 2)) * K + k0 + (l & 3) * 8, &As[i * 512]);
            gload16(Bt + (size_t)(n0 + i * 16 + (l >> 2)) * K + k0 + (l & 3) * 8, &Bs[i * 512]);
        }
        __syncthreads();
        bf16x8 af[4], bf[4];
#pragma unroll
        for (int t = 0; t < 4; t++) {
            af[t] = *(const bf16x8*)&As[(wm * 64 + t * 16 + l15) * 32 + l4 * 8];
            bf[t] = *(const bf16x8*)&Bs[(wn * 64 + t * 16 + l15) * 32 + l4 * 8];
        }
#pragma unroll
        for (int mt = 0; mt < 4; mt++)
#pragma unroll
            for (int nt = 0; nt < 4; nt++)
                acc[mt][nt] = __builtin_amdgcn_mfma_f32_16x16x32_bf16(af[mt], bf[nt], acc[mt][nt], 0, 0, 0);
    }
#pragma unroll
    for (int mt = 0; mt < 4; mt++) {
#pragma unroll
        for (int nt = 0; nt < 4; nt++) {
            const int n = n0 + wn * 64 + nt * 16 + l15;
            const float bi = bias[n];
#pragma unroll
            for (int r = 0; r < 4; r++) {
                const int m = m0 + wm * 64 + mt * 16 + l4 * 4 + r;
                const size_t idx = (size_t)m * N + n;
                const float v = acc[mt][nt][r] + bi;
                if (mode == 0) {
                    Cf[idx] = v + resid[idx];
                } else if (mode == 1) {
                    Cb[idx] = f2bf(v);
                } else {
                    const float a = bf2f(Cb[idx]);
                    Cb[idx] = f2bf(a / (1.f + __expf(-a)) * v);
                }
            }
        }
    }
}

// ---------------- QKV GEMM: A=h [4096][1024], Bt=WqkvT [3072][1024]; scatter epilogue ----------------
__global__ __launch_bounds__(256) void gemm_qkv(const u16* __restrict__ A, const u16* __restrict__ Bt,
                                                u16* __restrict__ qo, u16* __restrict__ ko, u16* __restrict__ vto)
{
    __shared__ __align__(16) u16 As[128 * 32];
    __shared__ __align__(16) u16 Bs[128 * 32];
    const int tid = threadIdx.x, w = tid >> 6, l = tid & 63, l15 = l & 15, l4 = l >> 4;
    const int wm = w >> 1, wn = w & 1;
    const int n0 = blockIdx.x * 128, m0 = blockIdx.y * 128;
    const int K = N_EMBD;
    f32x4 acc[4][4] = {};
    for (int k0 = 0; k0 < K; k0 += 32) {
        __syncthreads();
#pragma unroll
        for (int c = 0; c < 2; c++) {
            const int i = w + c * 4;
            gload16(A  + (size_t)(m0 + i * 16 + (l >> 2)) * K + k0 + (l & 3) * 8, &As[i * 512]);
            gload16(Bt + (size_t)(n0 + i * 16 + (l >> 2)) * K + k0 + (l & 3) * 8, &Bs[i * 512]);
        }
        __syncthreads();
        bf16x8 af[4], bf[4];
#pragma unroll
        for (int t = 0; t < 4; t++) {
            af[t] = *(const bf16x8*)&As[(wm * 64 + t * 16 + l15) * 32 + l4 * 8];
            bf[t] = *(const bf16x8*)&Bs[(wn * 64 + t * 16 + l15) * 32 + l4 * 8];
        }
#pragma unroll
        for (int mt = 0; mt < 4; mt++)
#pragma unroll
            for (int nt = 0; nt < 4; nt++)
                acc[mt][nt] = __builtin_amdgcn_mfma_f32_16x16x32_bf16(af[mt], bf[nt], acc[mt][nt], 0, 0, 0);
    }
#pragma unroll
    for (int mt = 0; mt < 4; mt++) {
#pragma unroll
        for (int nt = 0; nt < 4; nt++) {
            const int n = n0 + wn * 64 + nt * 16 + l15;
            const int which = n >> 10, hd = (n >> 6) & 15, dd = n & 63;
            const int mb = m0 + wm * 64 + mt * 16 + l4 * 4;
            const int bI = mb >> 11, tq = mb & (T_SEQ - 1);
            if (which == 2) {
                ushort4 st = make_ushort4(f2bf(acc[mt][nt][0]), f2bf(acc[mt][nt][1]),
                                          f2bf(acc[mt][nt][2]), f2bf(acc[mt][nt][3]));
                *(ushort4*)(vto + ((size_t)(bI * N_HEAD + hd) * HEAD_SIZE + dd) * T_SEQ + tq) = st;
            } else {
                u16* dst = (which == 0) ? qo : ko;
#pragma unroll
                for (int r = 0; r < 4; r++)
                    dst[((size_t)(bI * N_HEAD + hd) * T_SEQ + tq + r) * HEAD_SIZE + dd] = f2bf(acc[mt][nt][r]);
            }
        }
    }
}

// ---------------- P-fragment cross-lane assembly for PV ----------------
// After swapped QK^T, lane (g=l4, q=l15) holds P[q][16t+4g+r]. PV B-frag needs
// P[q][l4*8+j] (+32 per half). pk pairs are exchanged among the 4 g-groups of a q-row.
__device__ __forceinline__ bf16x8 build_pb(int g, unsigned p00, unsigned p01, unsigned p10, unsigned p11)
{
    const bool hi2 = (g & 2) != 0;
    const unsigned z16a = hi2 ? p10 : p00, z16b = hi2 ? p11 : p01;
    const unsigned z32a = hi2 ? p00 : p10, z32b = hi2 ? p01 : p11;
    const unsigned r16a = (unsigned)__shfl_xor((int)z16a, 16);
    const unsigned r16b = (unsigned)__shfl_xor((int)z16b, 16);
    const unsigned r32a = (unsigned)__shfl_xor((int)z32a, 32);
    const unsigned r32b = (unsigned)__shfl_xor((int)z32b, 32);
    const unsigned r48a = (unsigned)__shfl_xor((int)z32a, 48);
    const unsigned r48b = (unsigned)__shfl_xor((int)z32b, 48);
    union { unsigned u[4]; bf16x8 v; } r;
    r.u[0] = (g == 0) ? z16a : (g == 1) ? r48a : (g == 2) ? r32a : r16a;
    r.u[1] = (g == 0) ? z16b : (g == 1) ? r48b : (g == 2) ? r32b : r16b;
    r.u[2] = (g == 0) ? r16a : (g == 1) ? r32a : (g == 2) ? r48a : z16a;
    r.u[3] = (g == 0) ? r16b : (g == 1) ? r32b : (g == 2) ? r48b : z16b;
    return r.v;
}

// ---------------- MFMA flash attention (swapped-QK orientation) ----------------
// grid = (T/64, B*H), 256 threads. Wave w: q rows q0+w*16..+15, lane owns q=l15.
__global__ __launch_bounds__(256) void attn_mfma(const u16* __restrict__ q, const u16* __restrict__ k,
                                                 const u16* __restrict__ vt, u16* __restrict__ o)
{
    __shared__ __align__(16) u16 Kb[64 * 64];
    __shared__ __align__(16) u16 Vb[64 * 64];
    const int tid = threadIdx.x, w = tid >> 6, l = tid & 63, l15 = l & 15, l4 = l >> 4;
    const int q0 = ((int)gridDim.x - 1 - (int)blockIdx.x) * 64;   // big blocks first
    const int bh = blockIdx.y;
    const int qw0 = q0 + w * 16;
    const u16* qb  = q  + (size_t)bh * T_SEQ * HEAD_SIZE;
    const u16* kbg = k  + (size_t)bh * T_SEQ * HEAD_SIZE;
    const u16* vbg = vt + (size_t)bh * HEAD_SIZE * T_SEQ;

    const bf16x8 qa0 = *(const bf16x8*)(qb + (size_t)(qw0 + l15) * HEAD_SIZE + l4 * 8);
    const bf16x8 qa1 = *(const bf16x8*)(qb + (size_t)(qw0 + l15) * HEAD_SIZE + 32 + l4 * 8);

    f32x4 oacc[4] = {};
    float mrow = -1e30f, lrow = 0.f;
    const float qs = 0.125f * 1.44269504088896f;   // 1/sqrt(64) * log2(e)

    const int srow = l >> 3;
    const int scol = (l & 7) * 16;   // byte col within 128B row

    for (int s0 = 0; s0 <= q0; s0 += 64) {
        __syncthreads();
        // stage K [ks][d] and Vt [d][ks] as XOR-swizzled bf16 via pre-swizzled global src
#pragma unroll
        for (int c = 0; c < 2; c++) {
            const int i = w * 2 + c;
            const int row = i * 8 + srow;
            const int sw = scol ^ ((row & 7) << 4);
            gload16((const char*)(kbg + (size_t)(s0 + row) * HEAD_SIZE) + sw, &Kb[i * 512]);
            gload16((const char*)(vbg + (size_t)row * T_SEQ + s0) + sw, &Vb[i * 512]);
        }
        __syncthreads();

        // S^T = K·Q^T : lane holds S[q=l15][ks = t*16 + l4*4 + r]
        f32x4 sa[4] = {};
#pragma unroll
        for (int t = 0; t < 4; t++) {
            const int row = t * 16 + l15;
            const int swz = (row & 7) << 4;
            const bf16x8 kf0 = *(const bf16x8*)((const char*)Kb + row * 128 + ((l4 * 16) ^ swz));
            const bf16x8 kf1 = *(const bf16x8*)((const char*)Kb + row * 128 + ((l4 * 16 + 64) ^ swz));
            sa[t] = __builtin_amdgcn_mfma_f32_16x16x32_bf16(kf0, qa0, sa[t], 0, 0, 0);
            sa[t] = __builtin_amdgcn_mfma_f32_16x16x32_bf16(kf1, qa1, sa[t], 0, 0, 0);
        }
        // causal mask (diagonal chunk only)
        if (s0 == q0) {
#pragma unroll
            for (int t = 0; t < 4; t++)
#pragma unroll
                for (int r = 0; r < 4; r++)
                    if (t * 16 + l4 * 4 + r > w * 16 + l15) sa[t][r] = -1e30f;
        }
        // online softmax (exp2 domain, scale folded into FMA)
        float rmax = sa[0][0];
#pragma unroll
        for (int t = 0; t < 4; t++)
#pragma unroll
            for (int r = 0; r < 4; r++) rmax = fmaxf(rmax, sa[t][r]);
        rmax = fmaxf(rmax, __shfl_xor(rmax, 16));
        rmax = fmaxf(rmax, __shfl_xor(rmax, 32));
        const float mnew  = fmaxf(mrow, rmax * qs);
        const float alpha = exp2f(mrow - mnew);
        mrow = mnew;
        float p[4][4];
        float ls = 0.f;
#pragma unroll
        for (int t = 0; t < 4; t++)
#pragma unroll
            for (int r = 0; r < 4; r++) {
                const float pv = exp2f(fmaf(sa[t][r], qs, -mnew));
                p[t][r] = pv;
                ls += pv;
            }
        ls += __shfl_xor(ls, 16);
        ls += __shfl_xor(ls, 32);
        lrow = lrow * alpha + ls;
#pragma unroll
        for (int dt = 0; dt < 4; dt++) {
            oacc[dt][0] *= alpha; oacc[dt][1] *= alpha;
            oacc[dt][2] *= alpha; oacc[dt][3] *= alpha;
        }
        // pack P pairs: pk[t][c] = bf16(p[t][2c]) | bf16(p[t][2c+1])<<16
        unsigned pk[4][2];
#pragma unroll
        for (int t = 0; t < 4; t++)
#pragma unroll
            for (int c = 0; c < 2; c++)
                pk[t][c] = (unsigned)f2bf(p[t][2 * c]) | ((unsigned)f2bf(p[t][2 * c + 1]) << 16);
        const bf16x8 pb0 = build_pb(l4, pk[0][0], pk[0][1], pk[1][0], pk[1][1]);
        const bf16x8 pb1 = build_pb(l4, pk[2][0], pk[2][1], pk[3][0], pk[3][1]);
        // O^T += V^T · P^T : lane holds O[q=l15][d = dt*16 + l4*4 + r]
#pragma unroll
        for (int dt = 0; dt < 4; dt++) {
            const int row = dt * 16 + l15;
            const int swz = (row & 7) << 4;
            const bf16x8 vf0 = *(const bf16x8*)((const char*)Vb + row * 128 + ((l4 * 16) ^ swz));
            const bf16x8 vf1 = *(const bf16x8*)((const char*)Vb + row * 128 + ((l4 * 16 + 64) ^ swz));
            oacc[dt] = __builtin_amdgcn_mfma_f32_16x16x32_bf16(vf0, pb0, oacc[dt], 0, 0, 0);
            oacc[dt] = __builtin_amdgcn_mfma_f32_16x16x32_bf16(vf1, pb1, oacc[dt], 0, 0, 0);
        }
    }
    const float inv = 1.f / lrow;
    const int bI = bh >> 4, hh = bh & 15;
    u16* ob = o + ((size_t)(bI * T_SEQ + qw0 + l15)) * N_EMBD + hh * HEAD_SIZE;
#pragma unroll
    for (int dt = 0; dt < 4; dt++) {
        ushort4 st = make_ushort4(f2bf(oacc[dt][0] * inv), f2bf(oacc[dt][1] * inv),
                                  f2bf(oacc[dt][2] * inv), f2bf(oacc[dt][3] * inv));
        *(ushort4*)(ob + dt * 16 + l4 * 4) = st;
    }
}

extern "C" void kernel_launch(void* const* d_in, const int* in_sizes, int n_in,
                              void* d_out, int out_size, void* d_ws, size_t ws_size,
                              hipStream_t stream)
{
    (void)in_sizes; (void)n_in; (void)out_size; (void)ws_size;
    const float* x      = (const float*)d_in[0];
    const float* ln1_w  = (const float*)d_in[1];
    const float* ln1_b  = (const float*)d_in[2];
    const float* ln2_w  = (const float*)d_in[3];
    const float* ln2_b  = (const float*)d_in[4];
    const float* Wq     = (const float*)d_in[5];
    const float* Wk     = (const float*)d_in[6];
    const float* Wv     = (const float*)d_in[7];
    const float* proj_w = (const float*)d_in[8];
    const float* proj_b = (const float*)d_in[9];
    const float* w_w    = (const float*)d_in[10];
    const float* w_b    = (const float*)d_in[11];
    const float* v_w    = (const float*)d_in[12];
    const float* v_b    = (const float*)d_in[13];
    const float* p_w    = (const float*)d_in[14];
    const float* p_b    = (const float*)d_in[15];
    float* out = (float*)d_out;

    char* W = (char*)d_ws;
    u16*   Wqkv = (u16*)(W + 0);          // [3072][1024] bf16, 6 MB
    u16*   pwT  = (u16*)(W + 6291456);    // [1024][1024], 2 MB
    u16*   wwT  = (u16*)(W + 8388608);    // [2048][1024], 4 MB
    u16*   vvT  = (u16*)(W + 12582912);   // [2048][1024], 4 MB
    u16*   ppT  = (u16*)(W + 16777216);   // [1024][2048], 4 MB
    u16*   h    = (u16*)(W + 20971520);   // [4096][1024] bf16 (LN1 out, later LN2 out)
    u16*   qB   = (u16*)(W + 29360128);   // [B,H,T,D] bf16
    u16*   kB   = (u16*)(W + 37748736);   // [B,H,T,D] bf16
    u16*   vtB  = (u16*)(W + 46137344);   // [B,H,D,T] bf16
    u16*   oB   = (u16*)(W + 54525952);   // [4096][1024] bf16
    float* x1   = (float*)(W + 62914560); // [4096][1024] f32 (ends at 76 MB)
    u16*   ga   = qB;                     // [4096][2048] bf16 over q+k (dead after attn)

    // weight prep (transpose + bf16 cast)
    wtrans<<<dim3(16, 1, 16), 256, 0, stream>>>(Wq, Wqkv,                64, 1024, 65536, 65536);
    wtrans<<<dim3(16, 1, 16), 256, 0, stream>>>(Wk, Wqkv + 1024 * 1024,  64, 1024, 65536, 65536);
    wtrans<<<dim3(16, 1, 16), 256, 0, stream>>>(Wv, Wqkv + 2048 * 1024,  64, 1024, 65536, 65536);
    wtrans<<<dim3(16, 16, 1), 256, 0, stream>>>(proj_w, pwT, 1024, 1024, 0, 0);
    wtrans<<<dim3(16, 32, 1), 256, 0, stream>>>(w_w, wwT, 2048, 1024, 0, 0);
    wtrans<<<dim3(16, 32, 1), 256, 0, stream>>>(v_w, vvT, 2048, 1024, 0, 0);
    wtrans<<<dim3(32, 16, 1), 256, 0, stream>>>(p_w, ppT, 1024, 2048, 0, 0);

    // 1. LN1 -> h (bf16)
    ln_kernel<<<ROWS, 256, 0, stream>>>(x, ln1_w, ln1_b, h);
    // 2. QKV GEMM -> q,k [B,H,T,D], vt [B,H,D,T]
    gemm_qkv<<<dim3(24, 32), 256, 0, stream>>>(h, Wqkv, qB, kB, vtB);
    // 3. RoPE on q,k
    rope_kernel<<<(BATCH * N_HEAD * T_SEQ * 32) / 256, 256, 0, stream>>>(qB, kB);
    // 4. attention -> o [B,T,C] bf16
    attn_mfma<<<dim3(T_SEQ / 64, BATCH * N_HEAD), 256, 0, stream>>>(qB, kB, vtB, oB);
    // 5. proj + bias + residual(x) -> x1 (f32)
    gemm_br<<<dim3(8, 32), 256, 0, stream>>>(oB, pwT, proj_b, x, x1, nullptr, N_EMBD, N_EMBD, 0);
    // 6. LN2 -> h (bf16, reused slot)
    ln_kernel<<<ROWS, 256, 0, stream>>>(x1, ln2_w, ln2_b, h);
    // 7. gate a = h2@w_w + w_b -> ga (bf16)
    gemm_br<<<dim3(16, 32), 256, 0, stream>>>(h, wwT, w_b, nullptr, nullptr, ga, HIDDEN, N_EMBD, 1);
    // 8. glu: ga = silu(ga) * (h2@v_w + v_b)
    gemm_br<<<dim3(16, 32), 256, 0, stream>>>(h, vvT, v_b, nullptr, nullptr, ga, HIDDEN, N_EMBD, 2);
    // 9. final: out = ga@p_w + p_b + x1 (f32)
    gemm_br<<<dim3(8, 32), 256, 0, stream>>>(ga, ppT, p_b, x1, out, nullptr, N_EMBD, HIDDEN, 0);
}

// Round 4
// 281.823 us; speedup vs baseline: 13.0006x; 1.2763x over previous
//
#include <hip/hip_runtime.h>
#include <math.h>

#define N_EMBD    1024
#define N_HEAD    16
#define HEAD_SIZE 64
#define T_SEQ     2048
#define BATCH     2
#define HIDDEN    2048
#define ROWS      4096

typedef __attribute__((ext_vector_type(8))) short bf16x8;
typedef __attribute__((ext_vector_type(4))) float f32x4;
typedef __attribute__((ext_vector_type(16))) float f32x16;
typedef unsigned short u16;

__device__ __forceinline__ u16 f2bf(float x) {
    union { float f; unsigned u; } v; v.f = x;
    unsigned r = v.u + 0x7fffu + ((v.u >> 16) & 1u);
    return (u16)(r >> 16);
}
__device__ __forceinline__ float bf2f(u16 h) {
    union { unsigned u; float f; } v; v.u = ((unsigned)h) << 16;
    return v.f;
}
__device__ __forceinline__ unsigned cvtpk_bf16(float lo, float hi) {
    unsigned r;
    asm volatile("v_cvt_pk_bf16_f32 %0, %1, %2" : "=v"(r) : "v"(lo), "v"(hi));
    return r;
}
__device__ __forceinline__ void gload16(const void* g, void* lds) {
    __builtin_amdgcn_global_load_lds((const __attribute__((address_space(1))) void*)g,
                                     (__attribute__((address_space(3))) void*)lds, 16, 0, 0);
}

// ================= weight transpose + bf16 cast =================
__device__ __forceinline__ void wtrans_body(const float* s, u16* d, int ldS, int ldD,
                                            int k0, int n0, float Ts[64][65])
{
    const int tid = threadIdx.x;
    const int rr = tid >> 4, c4 = (tid & 15) * 4;
#pragma unroll
    for (int i = 0; i < 4; i++) {
        float4 v = *(const float4*)(s + (size_t)(k0 + rr + i * 16) * ldS + n0 + c4);
        Ts[rr + i * 16][c4 + 0] = v.x;
        Ts[rr + i * 16][c4 + 1] = v.y;
        Ts[rr + i * 16][c4 + 2] = v.z;
        Ts[rr + i * 16][c4 + 3] = v.w;
    }
    __syncthreads();
    const int nr = tid >> 2, kc = (tid & 3) * 16;
#pragma unroll
    for (int j = 0; j < 4; j++) {
        u16 t0 = f2bf(Ts[kc + j * 4 + 0][nr]);
        u16 t1 = f2bf(Ts[kc + j * 4 + 1][nr]);
        u16 t2 = f2bf(Ts[kc + j * 4 + 2][nr]);
        u16 t3 = f2bf(Ts[kc + j * 4 + 3][nr]);
        *(ushort4*)(d + (size_t)(n0 + nr) * ldD + k0 + kc + j * 4) = make_ushort4(t0, t1, t2, t3);
    }
}

__global__ __launch_bounds__(256) void wtrans(const float* __restrict__ src, u16* __restrict__ dst,
                                              int ldS, int ldD)
{
    __shared__ float Ts[64][65];
    wtrans_body(src, dst, ldS, ldD, blockIdx.x * 64, blockIdx.y * 64, Ts);
}

// z = which*16 + head; src [1024][64] per head -> dst[z] = [64][1024]
__global__ __launch_bounds__(256) void wtrans_qkv(const float* __restrict__ Wq, const float* __restrict__ Wk,
                                                  const float* __restrict__ Wv, u16* __restrict__ dst)
{
    __shared__ float Ts[64][65];
    const int z = blockIdx.z;
    const int which = z >> 4;
    const float* s = (which == 0 ? Wq : (which == 1 ? Wk : Wv)) + (size_t)(z & 15) * 65536;
    wtrans_body(s, dst + (size_t)z * 65536, HEAD_SIZE, N_EMBD, blockIdx.x * 64, 0, Ts);
}

// z>>5: 0=w_w, 1=v_w ; both [1024][2048] -> [2048][1024]
__global__ __launch_bounds__(256) void wtrans_wv(const float* __restrict__ ww, const float* __restrict__ vv,
                                                 u16* __restrict__ dw, u16* __restrict__ dv)
{
    __shared__ float Ts[64][65];
    const int z = blockIdx.z;
    const float* s = (z >> 5) ? vv : ww;
    u16* d = (z >> 5) ? dv : dw;
    wtrans_body(s, d, HIDDEN, N_EMBD, blockIdx.x * 64, (z & 31) * 64, Ts);
}

// ================= LayerNorm f32 -> bf16 =================
__global__ __launch_bounds__(256) void ln_kernel(const float* __restrict__ x,
                                                 const float* __restrict__ w,
                                                 const float* __restrict__ b,
                                                 u16* __restrict__ out)
{
    const int row = blockIdx.x;
    const int tid = threadIdx.x;
    const float* xr = x + (size_t)row * N_EMBD;
    float4 v = *(const float4*)(xr + tid * 4);
    float s  = v.x + v.y + v.z + v.w;
    float s2 = v.x*v.x + v.y*v.y + v.z*v.z + v.w*v.w;
#pragma unroll
    for (int off = 32; off; off >>= 1) {
        s  += __shfl_xor(s, off);
        s2 += __shfl_xor(s2, off);
    }
    __shared__ float ss[4], ss2[4];
    if ((tid & 63) == 0) { ss[tid >> 6] = s; ss2[tid >> 6] = s2; }
    __syncthreads();
    s  = ss[0] + ss[1] + ss[2] + ss[3];
    s2 = ss2[0] + ss2[1] + ss2[2] + ss2[3];
    const float mean = s * (1.0f / N_EMBD);
    const float var  = s2 * (1.0f / N_EMBD) - mean * mean;
    const float rstd = rsqrtf(var + 1e-5f);
    float4 wv = *(const float4*)(w + tid * 4);
    float4 bv = *(const float4*)(b + tid * 4);
    ushort4 st = make_ushort4(f2bf((v.x - mean) * rstd * wv.x + bv.x),
                              f2bf((v.y - mean) * rstd * wv.y + bv.y),
                              f2bf((v.z - mean) * rstd * wv.z + bv.z),
                              f2bf((v.w - mean) * rstd * wv.w + bv.w));
    *(ushort4*)(out + (size_t)row * N_EMBD + tid * 4) = st;
}

// ================= RoPE on bf16 q,k =================
__global__ __launch_bounds__(256) void rope_kernel(u16* __restrict__ q, u16* __restrict__ k)
{
    const int u = blockIdx.x * 256 + threadIdx.x;
    const int i  = u & 31;
    const int t  = (u >> 5) & (T_SEQ - 1);
    const int bh = u >> 16;
    const size_t base = ((size_t)bh * T_SEQ + t) * HEAD_SIZE + 2 * i;
    const float L = 0.28782313662425572f;   // ln(10000)/32
    const int i0 = (2 * i) & 31, i1 = (2 * i + 1) & 31;
    float c0, s0, c1, s1;
    sincosf((float)t * __expf(-(float)i0 * L), &s0, &c0);
    sincosf((float)t * __expf(-(float)i1 * L), &s1, &c1);
    float a0 = bf2f(q[base]), a1 = bf2f(q[base + 1]);
    q[base]     = f2bf(a0 * c0 - a1 * s0);
    q[base + 1] = f2bf(a1 * c1 + a0 * s1);
    float b0 = bf2f(k[base]), b1 = bf2f(k[base + 1]);
    k[base]     = f2bf(b0 * c0 - b1 * s0);
    k[base + 1] = f2bf(b1 * c1 + b0 * s1);
}

// ================= MFMA GEMM (128x128, BK=32, 4 waves) : C = A·Bt^T + bias (+resid) =================
__global__ __launch_bounds__(256) void gemm_br(const u16* __restrict__ A, const u16* __restrict__ Bt,
                                               const float* __restrict__ bias, const float* __restrict__ resid,
                                               float* __restrict__ Cf,
                                               int N, int K)
{
    __shared__ __align__(16) u16 As[128 * 32];
    __shared__ __align__(16) u16 Bs[128 * 32];
    const int tid = threadIdx.x, w = tid >> 6, l = tid & 63, l15 = l & 15, l4 = l >> 4;
    const int wm = w >> 1, wn = w & 1;
    const int n0 = blockIdx.x * 128, m0 = blockIdx.y * 128;
    f32x4 acc[4][4] = {};
    for (int k0 = 0; k0 < K; k0 += 32) {
        __syncthreads();
#pragma unroll
        for (int c = 0; c < 2; c++) {
            const int i = w + c * 4;
            gload16(A  + (size_t)(m0 + i * 16 + (l >> 2)) * K + k0 + (l & 3) * 8, &As[i * 512]);
            gload16(Bt + (size_t)(n0 + i * 16 + (l >> 2)) * K + k0 + (l & 3) * 8, &Bs[i * 512]);
        }
        __syncthreads();
        bf16x8 af[4], bf[4];
#pragma unroll
        for (int t = 0; t < 4; t++) {
            af[t] = *(const bf16x8*)&As[(wm * 64 + t * 16 + l15) * 32 + l4 * 8];
            bf[t] = *(const bf16x8*)&Bs[(wn * 64 + t * 16 + l15) * 32 + l4 * 8];
        }
#pragma unroll
        for (int mt = 0; mt < 4; mt++)
#pragma unroll
            for (int nt = 0; nt < 4; nt++)
                acc[mt][nt] = __builtin_amdgcn_mfma_f32_16x16x32_bf16(af[mt], bf[nt], acc[mt][nt], 0, 0, 0);
    }
#pragma unroll
    for (int mt = 0; mt < 4; mt++) {
#pragma unroll
        for (int nt = 0; nt < 4; nt++) {
            const int n = n0 + wn * 64 + nt * 16 + l15;
            const float bi = bias[n];
#pragma unroll
            for (int r = 0; r < 4; r++) {
                const int m = m0 + wm * 64 + mt * 16 + l4 * 4 + r;
                const size_t idx = (size_t)m * N + n;
                Cf[idx] = acc[mt][nt][r] + bi + resid[idx];
            }
        }
    }
}

// ================= QKV GEMM with scatter epilogue =================
__global__ __launch_bounds__(256) void gemm_qkv(const u16* __restrict__ A, const u16* __restrict__ Bt,
                                                u16* __restrict__ qo, u16* __restrict__ ko, u16* __restrict__ vto)
{
    __shared__ __align__(16) u16 As[128 * 32];
    __shared__ __align__(16) u16 Bs[128 * 32];
    const int tid = threadIdx.x, w = tid >> 6, l = tid & 63, l15 = l & 15, l4 = l >> 4;
    const int wm = w >> 1, wn = w & 1;
    const int n0 = blockIdx.x * 128, m0 = blockIdx.y * 128;
    const int K = N_EMBD;
    f32x4 acc[4][4] = {};
    for (int k0 = 0; k0 < K; k0 += 32) {
        __syncthreads();
#pragma unroll
        for (int c = 0; c < 2; c++) {
            const int i = w + c * 4;
            gload16(A  + (size_t)(m0 + i * 16 + (l >> 2)) * K + k0 + (l & 3) * 8, &As[i * 512]);
            gload16(Bt + (size_t)(n0 + i * 16 + (l >> 2)) * K + k0 + (l & 3) * 8, &Bs[i * 512]);
        }
        __syncthreads();
        bf16x8 af[4], bf[4];
#pragma unroll
        for (int t = 0; t < 4; t++) {
            af[t] = *(const bf16x8*)&As[(wm * 64 + t * 16 + l15) * 32 + l4 * 8];
            bf[t] = *(const bf16x8*)&Bs[(wn * 64 + t * 16 + l15) * 32 + l4 * 8];
        }
#pragma unroll
        for (int mt = 0; mt < 4; mt++)
#pragma unroll
            for (int nt = 0; nt < 4; nt++)
                acc[mt][nt] = __builtin_amdgcn_mfma_f32_16x16x32_bf16(af[mt], bf[nt], acc[mt][nt], 0, 0, 0);
    }
#pragma unroll
    for (int mt = 0; mt < 4; mt++) {
#pragma unroll
        for (int nt = 0; nt < 4; nt++) {
            const int n = n0 + wn * 64 + nt * 16 + l15;
            const int which = n >> 10, hd = (n >> 6) & 15, dd = n & 63;
            const int mb = m0 + wm * 64 + mt * 16 + l4 * 4;
            const int bI = mb >> 11, tq = mb & (T_SEQ - 1);
            if (which == 2) {
                ushort4 st = make_ushort4(f2bf(acc[mt][nt][0]), f2bf(acc[mt][nt][1]),
                                          f2bf(acc[mt][nt][2]), f2bf(acc[mt][nt][3]));
                *(ushort4*)(vto + ((size_t)(bI * N_HEAD + hd) * HEAD_SIZE + dd) * T_SEQ + tq) = st;
            } else {
                u16* dst = (which == 0) ? qo : ko;
#pragma unroll
                for (int r = 0; r < 4; r++)
                    dst[((size_t)(bI * N_HEAD + hd) * T_SEQ + tq + r) * HEAD_SIZE + dd] = f2bf(acc[mt][nt][r]);
            }
        }
    }
}

// ================= Fused dual-GEMM GLU: ga = silu(h·Ww^T+wb) * (h·Wv^T+vb) =================
// 128M x 64N tile, 4 waves as 2m x 2n, per-wave 64x32.
__global__ __launch_bounds__(256) void gemm_glu(const u16* __restrict__ A, const u16* __restrict__ Bw,
                                                const u16* __restrict__ Bv,
                                                const float* __restrict__ wb, const float* __restrict__ vb,
                                                u16* __restrict__ G)
{
    __shared__ __align__(16) u16 As[128 * 32];
    __shared__ __align__(16) u16 Bws[64 * 32];
    __shared__ __align__(16) u16 Bvs[64 * 32];
    const int tid = threadIdx.x, w = tid >> 6, l = tid & 63, l15 = l & 15, l4 = l >> 4;
    const int wm = w >> 1, wn = w & 1;
    const int n0 = blockIdx.x * 64, m0 = blockIdx.y * 128;
    const int K = N_EMBD;
    f32x4 accA[4][2] = {};
    f32x4 accB[4][2] = {};
    for (int k0 = 0; k0 < K; k0 += 32) {
        __syncthreads();
#pragma unroll
        for (int c = 0; c < 2; c++) {
            const int i = w + c * 4;
            gload16(A + (size_t)(m0 + i * 16 + (l >> 2)) * K + k0 + (l & 3) * 8, &As[i * 512]);
        }
        gload16(Bw + (size_t)(n0 + w * 16 + (l >> 2)) * K + k0 + (l & 3) * 8, &Bws[w * 512]);
        gload16(Bv + (size_t)(n0 + w * 16 + (l >> 2)) * K + k0 + (l & 3) * 8, &Bvs[w * 512]);
        __syncthreads();
        bf16x8 af[4], bwf[2], bvf[2];
#pragma unroll
        for (int t = 0; t < 4; t++)
            af[t] = *(const bf16x8*)&As[(wm * 64 + t * 16 + l15) * 32 + l4 * 8];
#pragma unroll
        for (int u = 0; u < 2; u++) {
            bwf[u] = *(const bf16x8*)&Bws[(wn * 32 + u * 16 + l15) * 32 + l4 * 8];
            bvf[u] = *(const bf16x8*)&Bvs[(wn * 32 + u * 16 + l15) * 32 + l4 * 8];
        }
#pragma unroll
        for (int mt = 0; mt < 4; mt++)
#pragma unroll
            for (int u = 0; u < 2; u++) {
                accA[mt][u] = __builtin_amdgcn_mfma_f32_16x16x32_bf16(af[mt], bwf[u], accA[mt][u], 0, 0, 0);
                accB[mt][u] = __builtin_amdgcn_mfma_f32_16x16x32_bf16(af[mt], bvf[u], accB[mt][u], 0, 0, 0);
            }
    }
#pragma unroll
    for (int mt = 0; mt < 4; mt++) {
#pragma unroll
        for (int u = 0; u < 2; u++) {
            const int n = n0 + wn * 32 + u * 16 + l15;
            const float wbi = wb[n], vbi = vb[n];
#pragma unroll
            for (int r = 0; r < 4; r++) {
                const int m = m0 + wm * 64 + mt * 16 + l4 * 4 + r;
                const float a  = accA[mt][u][r] + wbi;
                const float bb = accB[mt][u][r] + vbi;
                G[(size_t)m * HIDDEN + n] = f2bf(a / (1.f + __expf(-a)) * bb);
            }
        }
    }
}

// ================= MFMA flash attention, 32x32 fragments =================
// grid = (T/64, B*H), 128 threads (2 waves). Wave w: q rows q0+w*32 .. +31; lane owns q = l&31.
__global__ __launch_bounds__(128) void attn_mfma(const u16* __restrict__ q, const u16* __restrict__ k,
                                                 const u16* __restrict__ vt, u16* __restrict__ o)
{
    __shared__ __align__(16) u16 Kb[64 * 64];
    __shared__ __align__(16) u16 Vb[64 * 64];
    const int tid = threadIdx.x, w = tid >> 6, l = tid & 63, l31 = l & 31, hh2 = l >> 5;
    const int q0 = ((int)gridDim.x - 1 - (int)blockIdx.x) * 64;   // big blocks first
    const int bh = blockIdx.y;
    const int qw0 = q0 + w * 32;
    const u16* qb  = q  + (size_t)bh * T_SEQ * HEAD_SIZE;
    const u16* kbg = k  + (size_t)bh * T_SEQ * HEAD_SIZE;
    const u16* vbg = vt + (size_t)bh * HEAD_SIZE * T_SEQ;

    // Q B-frags: qB[kk] = Q[qw0+l31][kk*16 + hh2*8 .. +7]
    bf16x8 qf[4];
    {
        const u16* qr = qb + (size_t)(qw0 + l31) * HEAD_SIZE + hh2 * 8;
#pragma unroll
        for (int kk = 0; kk < 4; kk++) qf[kk] = *(const bf16x8*)(qr + kk * 16);
    }

    f32x16 oacc[2] = {};
    float mrow = -1e30f, lrow = 0.f;
    const float qs = 0.125f * 1.44269504088896f;   // 1/sqrt(64) * log2(e)

    for (int s0 = 0; s0 <= q0; s0 += 64) {
        __syncthreads();
        // stage K [ks 64][d 64] and Vt [d 64][ks 64] bf16, XOR-swizzled via pre-swizzled global src
#pragma unroll
        for (int c = 0; c < 4; c++) {
            const int slot = c * 128 + tid;       // 16B slots, 512 per buffer
            const int row = slot >> 3;
            const int colb = (slot & 7) * 16;
            const int sw = colb ^ ((row & 7) << 4);
            gload16((const char*)(kbg + (size_t)(s0 + row) * HEAD_SIZE) + sw, (char*)Kb + slot * 16);
            gload16((const char*)(vbg + (size_t)row * T_SEQ + s0) + sw, (char*)Vb + slot * 16);
        }
        __syncthreads();

        // S^T tiles: sa[t] = K[t*32.. ][:] · Q^T ; lane: col q=l31, rows R(reg)=(reg&3)+8*(reg>>2)+4*hh2
        f32x16 sa[2] = {};
#pragma unroll
        for (int t = 0; t < 2; t++) {
            const int row = t * 32 + l31;
            const int swz = (row & 7) << 4;
#pragma unroll
            for (int kk = 0; kk < 4; kk++) {
                const bf16x8 kf = *(const bf16x8*)((const char*)Kb + row * 128 + ((kk * 32 + hh2 * 16) ^ swz));
                sa[t] = __builtin_amdgcn_mfma_f32_32x32x16_bf16(kf, qf[kk], sa[t], 0, 0, 0);
            }
        }
        // causal mask (diagonal chunk only)
        if (s0 == q0) {
#pragma unroll
            for (int t = 0; t < 2; t++)
#pragma unroll
                for (int reg = 0; reg < 16; reg++) {
                    const int R = (reg & 3) + 8 * (reg >> 2) + 4 * hh2;
                    if (t * 32 + R > w * 32 + l31) sa[t][reg] = -1e30f;
                }
        }
        // online softmax (exp2 domain)
        float rmax = sa[0][0];
#pragma unroll
        for (int t = 0; t < 2; t++)
#pragma unroll
            for (int reg = 0; reg < 16; reg++) rmax = fmaxf(rmax, sa[t][reg]);
        rmax = fmaxf(rmax, __shfl_xor(rmax, 32));
        const float mnew  = fmaxf(mrow, rmax * qs);
        const float alpha = exp2f(mrow - mnew);
        mrow = mnew;
        float ls = 0.f;
#pragma unroll
        for (int t = 0; t < 2; t++)
#pragma unroll
            for (int reg = 0; reg < 16; reg++) {
                const float pv = exp2f(fmaf(sa[t][reg], qs, -mnew));
                sa[t][reg] = pv;
                ls += pv;
            }
        ls += __shfl_xor(ls, 32);
        lrow = lrow * alpha + ls;
#pragma unroll
        for (int dt = 0; dt < 2; dt++)
#pragma unroll
            for (int reg = 0; reg < 16; reg++) oacc[dt][reg] *= alpha;

        // pack P pairs (regs 2j,2j+1 are consecutive ks)
        unsigned pkA[8], pkB[8];
#pragma unroll
        for (int j = 0; j < 8; j++) {
            pkA[j] = cvtpk_bf16(sa[0][2 * j], sa[0][2 * j + 1]);
            pkB[j] = cvtpk_bf16(sa[1][2 * j], sa[1][2 * j + 1]);
        }
        // PV B-frags: per K=16 step, lane needs P[ks0 + hh2*8 + j][q]
        bf16x8 pf[4];
        {
            union { unsigned u[4]; bf16x8 v; } r;
#pragma unroll
            for (int st = 0; st < 4; st++) {
                const unsigned* pk = (st < 2) ? pkA : pkB;
                const int b = (st & 1) * 4;
                const unsigned s0w = (unsigned)__shfl_xor((int)pk[b + 0], 32);
                const unsigned s1w = (unsigned)__shfl_xor((int)pk[b + 1], 32);
                const unsigned s2w = (unsigned)__shfl_xor((int)pk[b + 2], 32);
                const unsigned s3w = (unsigned)__shfl_xor((int)pk[b + 3], 32);
                r.u[0] = hh2 ? s2w : pk[b + 0];
                r.u[1] = hh2 ? s3w : pk[b + 1];
                r.u[2] = hh2 ? pk[b + 2] : s0w;
                r.u[3] = hh2 ? pk[b + 3] : s1w;
                pf[st] = r.v;
            }
        }
        // O^T += V^T · P^T : oacc[dt] covers rows d = dt*32 + R(reg), col q = l31
#pragma unroll
        for (int dt = 0; dt < 2; dt++) {
            const int row = dt * 32 + l31;
            const int swz = (row & 7) << 4;
#pragma unroll
            for (int st = 0; st < 4; st++) {
                const bf16x8 vf = *(const bf16x8*)((const char*)Vb + row * 128 + ((st * 32 + hh2 * 16) ^ swz));
                oacc[dt] = __builtin_amdgcn_mfma_f32_32x32x16_bf16(vf, pf[st], oacc[dt], 0, 0, 0);
            }
        }
    }

    const float inv = 1.f / lrow;
    const int bI = bh >> 4, hd = bh & 15;
    u16* ob = o + ((size_t)(bI * T_SEQ + qw0 + l31)) * N_EMBD + hd * HEAD_SIZE;
#pragma unroll
    for (int dt = 0; dt < 2; dt++)
#pragma unroll
        for (int g = 0; g < 4; g++) {
            const int d0 = dt * 32 + g * 8 + hh2 * 4;
            ushort4 st = make_ushort4(f2bf(oacc[dt][4 * g + 0] * inv), f2bf(oacc[dt][4 * g + 1] * inv),
                                      f2bf(oacc[dt][4 * g + 2] * inv), f2bf(oacc[dt][4 * g + 3] * inv));
            *(ushort4*)(ob + d0) = st;
        }
}

extern "C" void kernel_launch(void* const* d_in, const int* in_sizes, int n_in,
                              void* d_out, int out_size, void* d_ws, size_t ws_size,
                              hipStream_t stream)
{
    (void)in_sizes; (void)n_in; (void)out_size; (void)ws_size;
    const float* x      = (const float*)d_in[0];
    const float* ln1_w  = (const float*)d_in[1];
    const float* ln1_b  = (const float*)d_in[2];
    const float* ln2_w  = (const float*)d_in[3];
    const float* ln2_b  = (const float*)d_in[4];
    const float* Wq     = (const float*)d_in[5];
    const float* Wk     = (const float*)d_in[6];
    const float* Wv     = (const float*)d_in[7];
    const float* proj_w = (const float*)d_in[8];
    const float* proj_b = (const float*)d_in[9];
    const float* w_w    = (const float*)d_in[10];
    const float* w_b    = (const float*)d_in[11];
    const float* v_w    = (const float*)d_in[12];
    const float* v_b    = (const float*)d_in[13];
    const float* p_w    = (const float*)d_in[14];
    const float* p_b    = (const float*)d_in[15];
    float* out = (float*)d_out;

    char* W = (char*)d_ws;
    u16*   Wqkv = (u16*)(W + 0);          // [3072][1024] bf16, 6 MB
    u16*   pwT  = (u16*)(W + 6291456);    // [1024][1024], 2 MB
    u16*   wwT  = (u16*)(W + 8388608);    // [2048][1024], 4 MB
    u16*   vvT  = (u16*)(W + 12582912);   // [2048][1024], 4 MB
    u16*   ppT  = (u16*)(W + 16777216);   // [1024][2048], 4 MB
    u16*   h    = (u16*)(W + 20971520);   // [4096][1024] bf16 (LN1 out, later LN2 out)
    u16*   qB   = (u16*)(W + 29360128);   // [B,H,T,D] bf16
    u16*   kB   = (u16*)(W + 37748736);   // [B,H,T,D] bf16
    u16*   vtB  = (u16*)(W + 46137344);   // [B,H,D,T] bf16
    u16*   oB   = (u16*)(W + 54525952);   // [4096][1024] bf16
    float* x1   = (float*)(W + 62914560); // [4096][1024] f32 (ends at 76 MB)
    u16*   ga   = qB;                     // [4096][2048] bf16 over q+k (dead after attn)

    // weight prep (transpose + bf16 cast) — 4 launches
    wtrans_qkv<<<dim3(16, 1, 48), 256, 0, stream>>>(Wq, Wk, Wv, Wqkv);
    wtrans_wv<<<dim3(16, 1, 64), 256, 0, stream>>>(w_w, v_w, wwT, vvT);
    wtrans<<<dim3(16, 16), 256, 0, stream>>>(proj_w, pwT, 1024, 1024);
    wtrans<<<dim3(32, 16), 256, 0, stream>>>(p_w, ppT, 1024, 2048);

    // 1. LN1 -> h (bf16)
    ln_kernel<<<ROWS, 256, 0, stream>>>(x, ln1_w, ln1_b, h);
    // 2. QKV GEMM -> q,k [B,H,T,D], vt [B,H,D,T]
    gemm_qkv<<<dim3(24, 32), 256, 0, stream>>>(h, Wqkv, qB, kB, vtB);
    // 3. RoPE on q,k
    rope_kernel<<<(BATCH * N_HEAD * T_SEQ * 32) / 256, 256, 0, stream>>>(qB, kB);
    // 4. attention -> o [B,T,C] bf16
    attn_mfma<<<dim3(T_SEQ / 64, BATCH * N_HEAD), 128, 0, stream>>>(qB, kB, vtB, oB);
    // 5. proj + bias + residual(x) -> x1 (f32)
    gemm_br<<<dim3(8, 32), 256, 0, stream>>>(oB, pwT, proj_b, x, x1, N_EMBD, N_EMBD);
    // 6. LN2 -> h (bf16, reused)
    ln_kernel<<<ROWS, 256, 0, stream>>>(x1, ln2_w, ln2_b, h);
    // 7. fused GLU -> ga (bf16)
    gemm_glu<<<dim3(32, 32), 256, 0, stream>>>(h, wwT, vvT, w_b, v_b, ga);
    // 8. final: out = ga·p_w + p_b + x1 (f32)
    gemm_br<<<dim3(8, 32), 256, 0, stream>>>(ga, ppT, p_b, x1, out, N_EMBD, HIDDEN);
}